// Round 6
// baseline (282.557 us; speedup 1.0000x reference)
//
#include <hip/hip_runtime.h>

// VQ layer B=16,D=64,T=8192,E=512 — MFMA prefilter + exact numpy-fp32 windowed refine.
// Frozen exact recipe (r2/r5, absmax 0): s1=pairwise-8; G=seq-k FMA; c2=seq outer;
// key=(s1-2G)+c2 left-assoc; first-index strict-min.
// Round 6: latency-bound fixes. c2 -> prep kernel; no LDS staging (frags direct from
// L2-hot ws); codes split across wave pairs (2048 blocks, shorter waves); shuffle
// butterfly min1/min2 combine (no 32-way-conflict LDS transpose).

constexpr int Dc = 64, Ec = 512, Tc = 8192;
constexpr int QTOT = 131072, ZQ = 8388608;
constexpr int QPB = 64;   // queries per block (2 q-tiles x 2 code-halves = 4 waves)

using short8 = __attribute__((ext_vector_type(8))) short;
using f32x16 = __attribute__((ext_vector_type(16))) float;

__device__ __forceinline__ unsigned short bf16rn(float f) {
    unsigned u = __float_as_uint(f);
    unsigned r = u + 0x7FFFu + ((u >> 16) & 1u);
    return (unsigned short)(r >> 16);
}

// prep: (a) split codebook into bf16 hi/lo B-frags (validated r5 layout),
//       (b) c2 numpy-exact (seq outer-axis) -> ws float[512] at byte 131072.
__global__ void vq_prep(const float* __restrict__ cbfull, const int* __restrict__ cbidx,
                        unsigned short* __restrict__ ws16) {
    int tid = blockIdx.x * 256 + threadIdx.x;
    const float* cb = cbfull + (size_t)(cbidx[0] & 3) * (Dc * Ec);
    if (tid < 512) {
        int j = tid;
        float c = cb[j];
        float a = __fmul_rn(c, c);
        for (int d = 1; d < Dc; ++d) { c = cb[d * Ec + j]; a = __fadd_rn(a, __fmul_rn(c, c)); }
        ((float*)(ws16 + 65536))[j] = a;
    }
    if (tid >= 16 * 4 * 64) return;
    int l = tid & 63, c = (tid >> 6) & 3, g = tid >> 8;
    int n = g * 32 + (l & 31);
    int kbase = c * 16 + (l >> 5) * 8;
    size_t bh = ((size_t)((g * 4 + c) * 2 + 0) * 512) + l * 8;
    size_t bl = ((size_t)((g * 4 + c) * 2 + 1) * 512) + l * 8;
    #pragma unroll
    for (int i = 0; i < 8; ++i) {
        float v = cb[(kbase + i) * Ec + n];
        unsigned short h = bf16rn(v);
        float hf = __uint_as_float((unsigned)h << 16);
        ws16[bh + i] = h;
        ws16[bl + i] = bf16rn(v - hf);
    }
}

__global__ __launch_bounds__(256, 5) void vq_main(
    const float* __restrict__ z, const float* __restrict__ cbfull,
    const int* __restrict__ cbidx, const unsigned short* __restrict__ ws16,
    float* __restrict__ out) {
    __shared__ float s_c2[Ec];
    __shared__ unsigned s_w[QPB];
    __shared__ int s_idx[QPB];
    __shared__ unsigned s_p1[QPB], s_p2[QPB];

    const int tid = threadIdx.x;
    const int lane = tid & 63;
    const int wave = __builtin_amdgcn_readfirstlane(tid >> 6);  // 0..3
    const int qt = wave >> 1, half = wave & 1;                  // q-tile, code-half
    const int col = lane & 31, hh = lane >> 5;
    const int q0 = blockIdx.x * QPB;
    const int b = q0 >> 13, t0 = q0 & (Tc - 1);
    const int myq = qt * 32 + col;          // query whose A-row this lane holds
    const int t = t0 + myq;

    const int ci = cbidx[0] & 3;
    const float* __restrict__ cb = cbfull + (size_t)ci * (Dc * Ec);

    // s_c2 from prep (2 coalesced loads/thread)
    for (int j = tid; j < Ec; j += 256) s_c2[j] = ((const float*)(ws16 + 65536))[j];

    // query vector -> registers
    float zv[32];
    const float* zp = z + (size_t)b * Dc * Tc + t;
    #pragma unroll
    for (int c = 0; c < 4; ++c)
        #pragma unroll
        for (int i = 0; i < 8; ++i)
            zv[c * 8 + i] = zp[(size_t)(c * 16 + hh * 8 + i) * Tc];

    // ambiguity window (upper bound on |numpy_key - mfma_key|), r5-validated
    float s1p = 0.f;
    #pragma unroll
    for (int e = 0; e < 32; ++e) s1p = __fmaf_rn(zv[e], zv[e], s1p);
    float s1b = (s1p + __shfl_xor(s1p, 32, 64)) * 1.001f + 0.01f;
    float wf = 3.1e-7f * (s1b + 1.f) + 4.2e-6f * sqrtf(s1b) + 2.1e-5f;
    unsigned w_int = (s1b > 880.f) ? 0x7FFFFFFFu : (unsigned)(wf * 2.147483648e9f) + 512u;
    if (half == 0 && lane < 32) s_w[myq] = w_int;

    // A-frags: -2z split to bf16 hi/lo
    short8 uhf[4], ulf[4];
    #pragma unroll
    for (int c = 0; c < 4; ++c)
        #pragma unroll
        for (int i = 0; i < 8; ++i) {
            float f = -2.0f * zv[c * 8 + i];
            unsigned short h = bf16rn(f);
            float hf = __uint_as_float((unsigned)h << 16);
            uhf[c][i] = (short)h;
            ulf[c][i] = (short)bf16rn(f - hf);
        }

    __syncthreads();   // s_c2, s_w ready

    // GEMM over this wave's 8 code-groups; streaming min1/min2 of packed keys
    unsigned m1[16], m2[16];
    #pragma unroll
    for (int r = 0; r < 16; ++r) { m1[r] = 0xFFFFFFFFu; m2[r] = 0xFFFFFFFFu; }

    #pragma unroll 2
    for (int gi = 0; gi < 8; ++gi) {
        const int g = half * 8 + gi;
        const unsigned short* fb = ws16 + (size_t)(g * 8) * 512;
        const float kb = s_c2[g * 32 + col];
        f32x16 acc;
        #pragma unroll
        for (int r = 0; r < 16; ++r) acc[r] = kb;
        #pragma unroll
        for (int c = 0; c < 4; ++c) {
            short8 chf = *(const short8*)(fb + (size_t)(c * 2 + 0) * 512 + lane * 8);
            short8 clf = *(const short8*)(fb + (size_t)(c * 2 + 1) * 512 + lane * 8);
            acc = __builtin_amdgcn_mfma_f32_32x32x16_bf16(uhf[c], chf, acc, 0, 0, 0);
            acc = __builtin_amdgcn_mfma_f32_32x32x16_bf16(uhf[c], clf, acc, 0, 0, 0);
            acc = __builtin_amdgcn_mfma_f32_32x32x16_bf16(ulf[c], chf, acc, 0, 0, 0);
        }
        const unsigned jj = (unsigned)(g * 32 + col);
        #pragma unroll
        for (int r = 0; r < 16; ++r) {
            unsigned key = (__float_as_uint(acc[r] + 3.0f) << 9) | jj;  // exp fixed in [2,4)
            unsigned mx = key > m1[r] ? key : m1[r];
            m1[r] = key < m1[r] ? key : m1[r];
            m2[r] = mx < m2[r] ? mx : m2[r];
        }
    }

    // min1/min2 butterfly across the 32 code-cols (stays within hh half)
    #pragma unroll
    for (int st = 1; st < 32; st <<= 1) {
        #pragma unroll
        for (int r = 0; r < 16; ++r) {
            unsigned o1 = __shfl_xor(m1[r], st, 64);
            unsigned o2 = __shfl_xor(m2[r], st, 64);
            unsigned mx = m1[r] > o1 ? m1[r] : o1;
            m1[r] = m1[r] < o1 ? m1[r] : o1;
            m2[r] = m2[r] < o2 ? m2[r] : o2;
            m2[r] = m2[r] < mx ? m2[r] : mx;
        }
    }

    // publish half-0 pairs; merge in half-1 (packed keys: lower j wins ties = numpy)
    #pragma unroll
    for (int r = 0; r < 16; ++r) {
        if (half == 0 && col == r) {
            int row = (r & 3) + 8 * (r >> 2) + 4 * hh;   // verified 32x32 C/D row map
            s_p1[qt * 32 + row] = m1[r];
            s_p2[qt * 32 + row] = m2[r];
        }
    }
    __syncthreads();

    unsigned long long mask = 0;
    #pragma unroll
    for (int r = 0; r < 16; ++r) {
        bool amb = false;
        if (half == 1 && col == r) {
            int row = (r & 3) + 8 * (r >> 2) + 4 * hh;
            int Q = qt * 32 + row;
            unsigned a1 = s_p1[Q], a2 = s_p2[Q];
            unsigned mx = a1 > m1[r] ? a1 : m1[r];
            unsigned F1 = a1 < m1[r] ? a1 : m1[r];
            unsigned F2 = a2 < m2[r] ? a2 : m2[r];
            F2 = F2 < mx ? F2 : mx;
            s_idx[Q] = (int)(F1 & 511u);
            unsigned wq = s_w[Q];
            amb = ((unsigned long long)F2 <= (unsigned long long)F1 + wq);
        }
        mask |= __ballot(amb);   // bit = lane = hh*32 + r
    }

    // exact rescan (frozen numpy-fp32 recipe, all 512 codes) for ambiguous queries
    while (mask) {
        int L = __ffsll(mask) - 1; mask &= mask - 1;
        int r = L & 31, hb = L >> 5;
        int Q = qt * 32 + (r & 3) + 8 * (r >> 2) + 4 * hb;
        const float* zq = z + (size_t)b * Dc * Tc + (t0 + Q);
        float zr[64];
        #pragma unroll
        for (int d = 0; d < 64; ++d) zr[d] = zq[(size_t)d * Tc];
        float rr[8];
        #pragma unroll
        for (int u = 0; u < 8; ++u) rr[u] = __fmul_rn(zr[u], zr[u]);
        #pragma unroll
        for (int i = 8; i < 64; i += 8)
            #pragma unroll
            for (int u = 0; u < 8; ++u)
                rr[u] = __fadd_rn(rr[u], __fmul_rn(zr[i + u], zr[i + u]));
        float s1 = __fadd_rn(__fadd_rn(__fadd_rn(rr[0], rr[1]), __fadd_rn(rr[2], rr[3])),
                             __fadd_rn(__fadd_rn(rr[4], rr[5]), __fadd_rn(rr[6], rr[7])));
        float bk = __int_as_float(0x7f800000);
        int bj = 0;
        for (int u = 0; u < 8; ++u) {
            int j = u * 64 + lane;
            float G = 0.f;
            #pragma unroll
            for (int d = 0; d < 64; ++d) G = __fmaf_rn(zr[d], cb[d * Ec + j], G);
            float key = __fadd_rn(__fsub_rn(s1, __fmul_rn(2.0f, G)), s_c2[j]);
            if (key < bk) { bk = key; bj = j; }
        }
        #pragma unroll
        for (int m = 1; m < 64; m <<= 1) {
            float pk = __shfl_xor(bk, m, 64);
            int pj = __shfl_xor(bj, m, 64);
            if (pk < bk || (pk == bk && pj < bj)) { bk = pk; bj = pj; }
        }
        if (lane == 0) s_idx[Q] = bj;
    }
    __syncthreads();

    // epilogue: wave w owns dims [16w,16w+16); lane = local query
    {
        const int jj = s_idx[lane];
        const int tt = t0 + lane;
        float* op = out + ((size_t)b * Dc + wave * 16) * Tc + tt;
        #pragma unroll
        for (int dd = 0; dd < 16; ++dd)
            op[(size_t)dd * Tc] = cb[(wave * 16 + dd) * Ec + jj];
        if (wave == 0) out[ZQ + q0 + lane] = (float)jj;
    }
}

extern "C" void kernel_launch(void* const* d_in, const int* in_sizes, int n_in,
                              void* d_out, int out_size, void* d_ws, size_t ws_size,
                              hipStream_t stream) {
    const float* z = (const float*)d_in[0];
    const float* cbfull = (const float*)d_in[1];
    const int* cbidx = (const int*)d_in[2];
    unsigned short* ws16 = (unsigned short*)d_ws;
    float* out = (float*)d_out;

    hipLaunchKernelGGL(vq_prep, dim3(16), dim3(256), 0, stream, cbfull, cbidx, ws16);
    hipLaunchKernelGGL(vq_main, dim3(QTOT / QPB), dim3(256), 0, stream,
                       z, cbfull, cbidx, ws16, out);
}

// Round 8
// 226.245 us; speedup vs baseline: 1.2489x; 1.2489x over previous
//
#include <hip/hip_runtime.h>

// VQ layer B=16,D=64,T=8192,E=512 — MFMA prefilter + exact numpy-fp32 windowed refine.
// Frozen exact recipe (r2/r5, absmax 0): s1=pairwise-8; G=seq-k FMA; c2=seq outer;
// key=(s1-2G)+c2 left-assoc; first-index strict-min.
// Round 8: fix r7's staging bug (frags are 128KB = 128 slots, r7 staged 64KB and
// read OOB LDS for groups 8-15). Double-buffered 2x16KB chunk staging (2 groups
// per chunk, 8 chunks, 1 barrier/chunk), 4 blocks/CU. r6/r7 wins kept: prep c2,
// butterfly combine, one-pass epilogue.

constexpr int Dc = 64, Ec = 512, Tc = 8192;
constexpr int QTOT = 131072, ZQ = 8388608;
constexpr int QPB = 128;   // 4 waves x 32 queries; each wave scans all 512 codes

using short8 = __attribute__((ext_vector_type(8))) short;
using f32x16 = __attribute__((ext_vector_type(16))) float;

__device__ __forceinline__ unsigned short bf16rn(float f) {
    unsigned u = __float_as_uint(f);
    unsigned r = u + 0x7FFFu + ((u >> 16) & 1u);
    return (unsigned short)(r >> 16);
}

// prep: (a) codebook -> bf16 hi/lo B-frags (r5-validated layout, 128 x 1KB slots),
//       (b) c2 numpy-exact (seq outer-axis) -> ws float[512] at byte 131072.
__global__ void vq_prep(const float* __restrict__ cbfull, const int* __restrict__ cbidx,
                        unsigned short* __restrict__ ws16) {
    int tid = blockIdx.x * 256 + threadIdx.x;
    const float* cb = cbfull + (size_t)(cbidx[0] & 3) * (Dc * Ec);
    if (tid < 512) {
        int j = tid;
        float c = cb[j];
        float a = __fmul_rn(c, c);
        for (int d = 1; d < Dc; ++d) { c = cb[d * Ec + j]; a = __fadd_rn(a, __fmul_rn(c, c)); }
        ((float*)(ws16 + 65536))[j] = a;
    }
    if (tid >= 16 * 4 * 64) return;
    int l = tid & 63, c = (tid >> 6) & 3, g = tid >> 8;
    int n = g * 32 + (l & 31);
    int kbase = c * 16 + (l >> 5) * 8;
    size_t bh = ((size_t)((g * 4 + c) * 2 + 0) * 512) + l * 8;
    size_t bl = ((size_t)((g * 4 + c) * 2 + 1) * 512) + l * 8;
    #pragma unroll
    for (int i = 0; i < 8; ++i) {
        float v = cb[(kbase + i) * Ec + n];
        unsigned short h = bf16rn(v);
        float hf = __uint_as_float((unsigned)h << 16);
        ws16[bh + i] = h;
        ws16[bl + i] = bf16rn(v - hf);
    }
}

__global__ __launch_bounds__(256, 4) void vq_main(
    const float* __restrict__ z, const float* __restrict__ cbfull,
    const int* __restrict__ cbidx, const unsigned short* __restrict__ ws16,
    float* __restrict__ out) {
    // double buffer: chunk = 2 groups = 16 slots x 1KB = 16KB (8192 shorts)
    __shared__ __attribute__((aligned(16))) unsigned short s_frag[2][8192];
    __shared__ float s_c2[Ec];
    __shared__ unsigned s_w[QPB];
    __shared__ int s_idx[QPB];

    const int tid = threadIdx.x;
    const int lane = tid & 63;
    const int wave = __builtin_amdgcn_readfirstlane(tid >> 6);  // 0..3 (SGPR)
    const int col = lane & 31, hh = lane >> 5;
    const int q0 = blockIdx.x * QPB;
    const int b = q0 >> 13, t0 = q0 & (Tc - 1);
    const int myq = wave * 32 + col;
    const int t = t0 + myq;

    const int ci = cbidx[0] & 3;
    const float* __restrict__ cb = cbfull + (size_t)ci * (Dc * Ec);
    const uint4* __restrict__ wsv = (const uint4*)ws16;   // 8192 uint4 of frag data

    // stage chunk 0 (uint4 coalesced: 4/thread = 16KB)
    {
        uint4* dst = (uint4*)s_frag[0];
        #pragma unroll
        for (int k = 0; k < 4; ++k) dst[tid + k * 256] = wsv[tid + k * 256];
    }
    // c2 from prep
    for (int j = tid; j < Ec; j += 256) s_c2[j] = ((const float*)(ws16 + 65536))[j];

    // query vector -> registers (overlaps staging latency)
    float zv[32];
    const float* zp = z + (size_t)b * Dc * Tc + t;
    #pragma unroll
    for (int c = 0; c < 4; ++c)
        #pragma unroll
        for (int i = 0; i < 8; ++i)
            zv[c * 8 + i] = zp[(size_t)(c * 16 + hh * 8 + i) * Tc];

    // ambiguity window (r5-validated constants)
    float s1p = 0.f;
    #pragma unroll
    for (int e = 0; e < 32; ++e) s1p = __fmaf_rn(zv[e], zv[e], s1p);
    float s1b = (s1p + __shfl_xor(s1p, 32, 64)) * 1.001f + 0.01f;
    float wf = 3.1e-7f * (s1b + 1.f) + 4.2e-6f * sqrtf(s1b) + 2.1e-5f;
    unsigned w_int = (s1b > 880.f) ? 0x7FFFFFFFu : (unsigned)(wf * 2.147483648e9f) + 512u;
    if (hh == 0) s_w[myq] = w_int;

    // A-frags: -2z split to bf16 hi/lo
    short8 uhf[4], ulf[4];
    #pragma unroll
    for (int c = 0; c < 4; ++c)
        #pragma unroll
        for (int i = 0; i < 8; ++i) {
            float f = -2.0f * zv[c * 8 + i];
            unsigned short h = bf16rn(f);
            float hf = __uint_as_float((unsigned)h << 16);
            uhf[c][i] = (short)h;
            ulf[c][i] = (short)bf16rn(f - hf);
        }

    __syncthreads();   // buf0 + c2 + s_w ready

    unsigned m1[16], m2[16];
    #pragma unroll
    for (int r = 0; r < 16; ++r) { m1[r] = 0xFFFFFFFFu; m2[r] = 0xFFFFFFFFu; }

    // 8 chunks x {prefetch next | compute 2 groups} ; 1 barrier per chunk
    #pragma unroll 1
    for (int chk = 0; chk < 8; ++chk) {
        if (chk < 7) {   // prefetch chunk chk+1 into the other buffer
            uint4* dst = (uint4*)s_frag[(chk + 1) & 1];
            const uint4* src = wsv + (size_t)(chk + 1) * 1024;
            #pragma unroll
            for (int k = 0; k < 4; ++k) dst[tid + k * 256] = src[tid + k * 256];
        }
        const unsigned short* fb = s_frag[chk & 1];
        #pragma unroll
        for (int gi = 0; gi < 2; ++gi) {
            const int g = chk * 2 + gi;
            const float kb = s_c2[g * 32 + col];
            f32x16 acc;
            #pragma unroll
            for (int r = 0; r < 16; ++r) acc[r] = kb;
            #pragma unroll
            for (int c = 0; c < 4; ++c) {
                short8 chf = *(const short8*)(fb + (size_t)(gi * 8 + c * 2 + 0) * 512 + lane * 8);
                short8 clf = *(const short8*)(fb + (size_t)(gi * 8 + c * 2 + 1) * 512 + lane * 8);
                acc = __builtin_amdgcn_mfma_f32_32x32x16_bf16(uhf[c], chf, acc, 0, 0, 0);
                acc = __builtin_amdgcn_mfma_f32_32x32x16_bf16(uhf[c], clf, acc, 0, 0, 0);
                acc = __builtin_amdgcn_mfma_f32_32x32x16_bf16(ulf[c], chf, acc, 0, 0, 0);
            }
            const unsigned jj = (unsigned)(g * 32 + col);
            #pragma unroll
            for (int r = 0; r < 16; ++r) {
                unsigned key = (__float_as_uint(acc[r] + 3.0f) << 9) | jj;  // exp fixed in [2,4)
                unsigned mx = key > m1[r] ? key : m1[r];
                m1[r] = key < m1[r] ? key : m1[r];
                m2[r] = mx < m2[r] ? mx : m2[r];
            }
        }
        __syncthreads();   // next buffer written & this buffer free
    }

    // min1/min2 butterfly across 32 code-cols (register-only)
    #pragma unroll
    for (int st = 1; st < 32; st <<= 1) {
        #pragma unroll
        for (int r = 0; r < 16; ++r) {
            unsigned o1 = __shfl_xor(m1[r], st, 64);
            unsigned o2 = __shfl_xor(m2[r], st, 64);
            unsigned mx = m1[r] > o1 ? m1[r] : o1;
            m1[r] = m1[r] < o1 ? m1[r] : o1;
            m2[r] = m2[r] < o2 ? m2[r] : o2;
            m2[r] = m2[r] < mx ? m2[r] : mx;
        }
    }

    // lane col<16 owns accumulator r=col (static extraction)
    unsigned F1 = 0xFFFFFFFFu, F2 = 0xFFFFFFFFu;
    #pragma unroll
    for (int r = 0; r < 16; ++r) if (col == r) { F1 = m1[r]; F2 = m2[r]; }
    bool amb = false;
    if (col < 16) {
        int row = (col & 3) + 8 * (col >> 2) + 4 * hh;   // verified 32x32 C/D row map
        int Q = wave * 32 + row;
        s_idx[Q] = (int)(F1 & 511u);
        unsigned wq = s_w[Q];
        amb = ((unsigned long long)F2 <= (unsigned long long)F1 + wq);
    }
    unsigned long long mask = __ballot(amb);

    // exact rescan (frozen numpy-fp32 recipe, all 512 codes) for ambiguous queries
    while (mask) {
        int L = __ffsll(mask) - 1; mask &= mask - 1;
        int r = L & 31, hb = L >> 5;
        int Q = wave * 32 + (r & 3) + 8 * (r >> 2) + 4 * hb;
        const float* zq = z + (size_t)b * Dc * Tc + (t0 + Q);
        float zr[64];
        #pragma unroll
        for (int d = 0; d < 64; ++d) zr[d] = zq[(size_t)d * Tc];
        float rr[8];
        #pragma unroll
        for (int u = 0; u < 8; ++u) rr[u] = __fmul_rn(zr[u], zr[u]);
        #pragma unroll
        for (int i = 8; i < 64; i += 8)
            #pragma unroll
            for (int u = 0; u < 8; ++u)
                rr[u] = __fadd_rn(rr[u], __fmul_rn(zr[i + u], zr[i + u]));
        float s1 = __fadd_rn(__fadd_rn(__fadd_rn(rr[0], rr[1]), __fadd_rn(rr[2], rr[3])),
                             __fadd_rn(__fadd_rn(rr[4], rr[5]), __fadd_rn(rr[6], rr[7])));
        float bk = __int_as_float(0x7f800000);
        int bj = 0;
        for (int u = 0; u < 8; ++u) {
            int j = u * 64 + lane;
            float G = 0.f;
            #pragma unroll
            for (int d = 0; d < 64; ++d) G = __fmaf_rn(zr[d], cb[d * Ec + j], G);
            float key = __fadd_rn(__fsub_rn(s1, __fmul_rn(2.0f, G)), s_c2[j]);
            if (key < bk) { bk = key; bj = j; }
        }
        #pragma unroll
        for (int m = 1; m < 64; m <<= 1) {
            float pk = __shfl_xor(bk, m, 64);
            int pj = __shfl_xor(bj, m, 64);
            if (pk < bk || (pk == bk && pj < bj)) { bk = pk; bj = pj; }
        }
        if (lane == 0) s_idx[Q] = bj;
    }
    __syncthreads();

    // epilogue: wave w owns dims [16w,16w+16); 128 queries via qh loop
    for (int qh = 0; qh < 2; ++qh) {
        const int ql = qh * 64 + lane;
        const int jj = s_idx[ql];
        const int tt = t0 + ql;
        float* op = out + ((size_t)b * Dc + wave * 16) * Tc + tt;
        #pragma unroll
        for (int dd = 0; dd < 16; ++dd)
            op[(size_t)dd * Tc] = cb[(wave * 16 + dd) * Ec + jj];
        if (wave == 0) out[ZQ + q0 + ql] = (float)jj;
    }
}

extern "C" void kernel_launch(void* const* d_in, const int* in_sizes, int n_in,
                              void* d_out, int out_size, void* d_ws, size_t ws_size,
                              hipStream_t stream) {
    const float* z = (const float*)d_in[0];
    const float* cbfull = (const float*)d_in[1];
    const int* cbidx = (const int*)d_in[2];
    unsigned short* ws16 = (unsigned short*)d_ws;
    float* out = (float*)d_out;

    hipLaunchKernelGGL(vq_prep, dim3(16), dim3(256), 0, stream, cbfull, cbidx, ws16);
    hipLaunchKernelGGL(vq_main, dim3(QTOT / QPB), dim3(256), 0, stream,
                       z, cbfull, cbidx, ws16, out);
}

// Round 9
// 105.278 us; speedup vs baseline: 2.6839x; 2.1490x over previous
//
#include <hip/hip_runtime.h>

// VQ layer B=16,D=64,T=8192,E=512 — f16 MFMA prefilter + exact numpy-fp32 windowed refine.
// Frozen exact recipe (r2..r8, absmax 0): s1=pairwise-8; G=seq-k FMA; c2=seq outer;
// key=(s1-2G)+c2 left-assoc; first-index strict-min.
// Round 9: f16 2-product approx (u_hi+u_lo vs c_hi only; c scaled x512, u = -16z so
// product scale = 2^-12 exact, no f16 subnormal hazard). Frags now 64KB -> ONE-SHOT
// LDS stage, ONE barrier, barrier-free GEMM (r8's dbuf alias-serialization removed).
// Window widened rigorously: err <= 2^-11 * 2*sqrt(s1) * ||c||, ||c|| < 8/512 hard.

constexpr int Dc = 64, Ec = 512, Tc = 8192;
constexpr int QTOT = 131072, ZQ = 8388608;
constexpr int QPB = 256;          // 8 waves x 32 queries
constexpr int NBLK = QTOT / QPB;  // 512 blocks = 2/CU

using half8  = __attribute__((ext_vector_type(8))) _Float16;
using f32x16 = __attribute__((ext_vector_type(16))) float;

// prep: (a) 64 slots x 1KB: wsf[(g*4+c)*512 + l*8 + i] = f16( cb[c*16+(l>>5)*8+i][g*32+(l&31)] * 512 )
//       (b) c2 numpy-exact (seq outer-axis) -> float[512] at wsf+32768
__global__ void vq_prep(const float* __restrict__ cbfull, const int* __restrict__ cbidx,
                        _Float16* __restrict__ wsf) {
    int tid = blockIdx.x * 256 + threadIdx.x;
    const float* cb = cbfull + (size_t)(cbidx[0] & 3) * (Dc * Ec);
    if (tid < 512) {
        float c = cb[tid];
        float a = __fmul_rn(c, c);
        for (int d = 1; d < Dc; ++d) { c = cb[d * Ec + tid]; a = __fadd_rn(a, __fmul_rn(c, c)); }
        ((float*)(wsf + 32768))[tid] = a;
    }
    if (tid >= 4096) return;
    int l = tid & 63, c = (tid >> 6) & 3, g = tid >> 8;
    int n = g * 32 + (l & 31);
    int kbase = c * 16 + (l >> 5) * 8;
    _Float16* dst = wsf + (size_t)(g * 4 + c) * 512 + l * 8;
    #pragma unroll
    for (int i = 0; i < 8; ++i)
        dst[i] = (_Float16)(cb[(kbase + i) * Ec + n] * 512.0f);
}

__global__ __launch_bounds__(512) void vq_main(
    const float* __restrict__ z, const float* __restrict__ cbfull,
    const int* __restrict__ cbidx, const _Float16* __restrict__ wsf,
    float* __restrict__ out) {
    __shared__ __attribute__((aligned(16))) _Float16 s_frag[32768];  // 64KB, static layout
    __shared__ float s_c2[Ec];
    __shared__ unsigned s_w[QPB];
    __shared__ int s_idx[QPB];

    const int tid = threadIdx.x;
    const int lane = tid & 63;
    const int wave = __builtin_amdgcn_readfirstlane(tid >> 6);  // 0..7 (SGPR)
    const int col = lane & 31, hh = lane >> 5;
    const int q0 = blockIdx.x * QPB;
    const int b = q0 >> 13, t0 = q0 & (Tc - 1);
    const int myq = wave * 32 + col;
    const int t = t0 + myq;

    const int ci = cbidx[0] & 3;
    const float* __restrict__ cb = cbfull + (size_t)ci * (Dc * Ec);

    // one-shot stage: 64KB frags, 8 uint4/thread, coalesced, static indices
    {
        const uint4* src = (const uint4*)wsf;
        uint4* dst = (uint4*)s_frag;
        #pragma unroll
        for (int k = 0; k < 8; ++k) dst[tid + k * 512] = src[tid + k * 512];
    }
    if (tid < 512) s_c2[tid] = ((const float*)(wsf + 32768))[tid];

    // query vector -> registers (lanes consecutive in t -> coalesced)
    float zv[32];
    const float* zp = z + (size_t)b * Dc * Tc + t;
    #pragma unroll
    for (int c = 0; c < 4; ++c)
        #pragma unroll
        for (int i = 0; i < 8; ++i)
            zv[c * 8 + i] = zp[(size_t)(c * 16 + hh * 8 + i) * Tc];

    // ambiguity window: |np_key - approx_key| <= 2*[2^-11*2*sqrt(s1)*||c|| + slack]
    float s1p = 0.f;
    #pragma unroll
    for (int e = 0; e < 32; ++e) s1p = __fmaf_rn(zv[e], zv[e], s1p);
    float s1b = (s1p + __shfl_xor(s1p, 32, 64)) * 1.001f + 0.01f;
    float wf = 2.5e-7f * (s1b + 1.f) + 3.2e-5f * sqrtf(s1b) + 1e-5f;
    unsigned w_int = (s1b > 880.f) ? 0x7FFFFFFFu : (unsigned)(wf * 2.147483648e9f) + 512u;
    if (hh == 0) s_w[myq] = w_int;

    // A-frags: u' = -16*z, f16 hi + lo (residual exact in f32 before rounding)
    half8 uhf[4], ulf[4];
    #pragma unroll
    for (int c = 0; c < 4; ++c)
        #pragma unroll
        for (int i = 0; i < 8; ++i) {
            float f = -16.0f * zv[c * 8 + i];
            _Float16 h = (_Float16)f;
            float hf = (float)h;
            uhf[c][i] = h;
            ulf[c][i] = (_Float16)(f - hf);
        }

    __syncthreads();   // frags + c2 ready; no more barriers until epilogue

    // GEMM: 16 groups x {4 ds_read_b128, 8 MFMA f16, pack+min1/min2}; waves independent
    unsigned m1[16], m2[16];
    #pragma unroll
    for (int r = 0; r < 16; ++r) { m1[r] = 0xFFFFFFFFu; m2[r] = 0xFFFFFFFFu; }

    #pragma unroll 2
    for (int g = 0; g < 16; ++g) {
        const float kb = s_c2[g * 32 + col] * 4096.0f;   // exact pow2 scale
        f32x16 acc;
        #pragma unroll
        for (int r = 0; r < 16; ++r) acc[r] = kb;
        #pragma unroll
        for (int c = 0; c < 4; ++c) {
            half8 chf = *(const half8*)(s_frag + (size_t)(g * 4 + c) * 512 + lane * 8);
            acc = __builtin_amdgcn_mfma_f32_32x32x16_f16(uhf[c], chf, acc, 0, 0, 0);
            acc = __builtin_amdgcn_mfma_f32_32x32x16_f16(ulf[c], chf, acc, 0, 0, 0);
        }
        const unsigned jj = (unsigned)(g * 32 + col);
        #pragma unroll
        for (int r = 0; r < 16; ++r) {
            // A = acc*2^-12; A+3 in [2,4) (s1<=880 guard) -> monotone packed key
            float keyf = __fmaf_rn(acc[r], 2.44140625e-4f, 3.0f);
            unsigned key = (__float_as_uint(keyf) << 9) | jj;
            unsigned mx = key > m1[r] ? key : m1[r];
            m1[r] = key < m1[r] ? key : m1[r];
            m2[r] = mx < m2[r] ? mx : m2[r];
        }
    }

    // min1/min2 butterfly across 32 code-cols (register-only)
    #pragma unroll
    for (int st = 1; st < 32; st <<= 1) {
        #pragma unroll
        for (int r = 0; r < 16; ++r) {
            unsigned o1 = __shfl_xor(m1[r], st, 64);
            unsigned o2 = __shfl_xor(m2[r], st, 64);
            unsigned mx = m1[r] > o1 ? m1[r] : o1;
            m1[r] = m1[r] < o1 ? m1[r] : o1;
            m2[r] = m2[r] < o2 ? m2[r] : o2;
            m2[r] = m2[r] < mx ? m2[r] : mx;
        }
    }

    // lane col<16 owns accumulator r=col (static extraction)
    unsigned F1 = 0xFFFFFFFFu, F2 = 0xFFFFFFFFu;
    #pragma unroll
    for (int r = 0; r < 16; ++r) if (col == r) { F1 = m1[r]; F2 = m2[r]; }
    bool amb = false;
    if (col < 16) {
        int row = (col & 3) + 8 * (col >> 2) + 4 * hh;   // verified 32x32 C/D row map
        int Q = wave * 32 + row;
        s_idx[Q] = (int)(F1 & 511u);                      // wave-local write
        unsigned wq = s_w[Q];                             // wave-local read
        amb = ((unsigned long long)F2 <= (unsigned long long)F1 + wq);
    }
    unsigned long long mask = __ballot(amb);

    // exact rescan (frozen numpy-fp32 recipe, all 512 codes) for ambiguous queries
    while (mask) {
        int L = __ffsll(mask) - 1; mask &= mask - 1;
        int r = L & 31, hb = L >> 5;
        int Q = wave * 32 + (r & 3) + 8 * (r >> 2) + 4 * hb;
        const float* zq = z + (size_t)b * Dc * Tc + (t0 + Q);
        float zr[64];
        #pragma unroll
        for (int d = 0; d < 64; ++d) zr[d] = zq[(size_t)d * Tc];
        float rr[8];
        #pragma unroll
        for (int u = 0; u < 8; ++u) rr[u] = __fmul_rn(zr[u], zr[u]);
        #pragma unroll
        for (int i = 8; i < 64; i += 8)
            #pragma unroll
            for (int u = 0; u < 8; ++u)
                rr[u] = __fadd_rn(rr[u], __fmul_rn(zr[i + u], zr[i + u]));
        float s1 = __fadd_rn(__fadd_rn(__fadd_rn(rr[0], rr[1]), __fadd_rn(rr[2], rr[3])),
                             __fadd_rn(__fadd_rn(rr[4], rr[5]), __fadd_rn(rr[6], rr[7])));
        float bk = __int_as_float(0x7f800000);
        int bj = 0;
        for (int u = 0; u < 8; ++u) {
            int j = u * 64 + lane;
            float G = 0.f;
            #pragma unroll
            for (int d = 0; d < 64; ++d) G = __fmaf_rn(zr[d], cb[d * Ec + j], G);
            float key = __fadd_rn(__fsub_rn(s1, __fmul_rn(2.0f, G)), s_c2[j]);
            if (key < bk) { bk = key; bj = j; }
        }
        #pragma unroll
        for (int m = 1; m < 64; m <<= 1) {
            float pk = __shfl_xor(bk, m, 64);
            int pj = __shfl_xor(bj, m, 64);
            if (pk < bk || (pk == bk && pj < bj)) { bk = pk; bj = pj; }
        }
        if (lane == 0) s_idx[Q] = bj;
    }
    __syncthreads();

    // epilogue: wave w owns dims [8w, 8w+8); 256 queries via qh loop
    #pragma unroll
    for (int qh = 0; qh < 4; ++qh) {
        const int ql = qh * 64 + lane;
        const int jj = s_idx[ql];
        const int tt = t0 + ql;
        float* op = out + ((size_t)b * Dc + wave * 8) * Tc + tt;
        #pragma unroll
        for (int dd = 0; dd < 8; ++dd)
            op[(size_t)dd * Tc] = cb[(wave * 8 + dd) * Ec + jj];
        if (wave == 0) out[ZQ + q0 + ql] = (float)jj;
    }
}

extern "C" void kernel_launch(void* const* d_in, const int* in_sizes, int n_in,
                              void* d_out, int out_size, void* d_ws, size_t ws_size,
                              hipStream_t stream) {
    const float* z = (const float*)d_in[0];
    const float* cbfull = (const float*)d_in[1];
    const int* cbidx = (const int*)d_in[2];
    _Float16* wsf = (_Float16*)d_ws;
    float* out = (float*)d_out;

    hipLaunchKernelGGL(vq_prep, dim3(16), dim3(256), 0, stream, cbfull, cbidx, wsf);
    hipLaunchKernelGGL(vq_main, dim3(NBLK), dim3(512), 0, stream,
                       z, cbfull, cbidx, wsf, out);
}